// Round 9
// baseline (249.790 us; speedup 1.0000x reference)
//
#include <hip/hip_runtime.h>

#define NT 1024      // N_TOPICS
#define TD 128       // TOPIC_DIM
#define HID 512      // HIDDEN
#define NH 8         // N_HEADS
#define HD 64        // HEAD_DIM
#define NB 8         // BATCH

typedef unsigned short us;
typedef _Float16 h16;
typedef h16 half8 __attribute__((ext_vector_type(8)));
typedef h16 h16x2 __attribute__((ext_vector_type(2)));
typedef float f32x4 __attribute__((ext_vector_type(4)));

#define LOG2E 1.44269504f

extern "C" __device__ _Float16 __ocml_exp2_f16(_Float16);

__device__ __forceinline__ us f2h(float x) { return __builtin_bit_cast(us, (h16)x); }
__device__ __forceinline__ float h2f(us s) { return (float)__builtin_bit_cast(h16, s); }
__device__ __forceinline__ unsigned int pkh2(float a, float b) {
    auto v = __builtin_amdgcn_cvt_pkrtz(a, b);
    return __builtin_bit_cast(unsigned int, v);
}

// ============ kprep: fused max-scan + TWu (0-1023) | node0 GEMM (1024-1151)
//              | gW transpose (1152-1279) | VAVS + ctx-zero (1280-1343)
// TWu = f16(exp2(tm*0.1*log2e)*log2e) or NaN where adj==0; tw = TWu*sfac.
// VAVS[n][i]: n<8 -> W2_n @ a_dst (ed2); n>=8 -> W2_(n-8) @ a_src (es2q).
__global__ __launch_bounds__(256) void kprep(const float* __restrict__ tm, const int* __restrict__ adj,
                                             float* __restrict__ part, us* __restrict__ TWb,
                                             const float* __restrict__ emb, const float* __restrict__ sW,
                                             const float* __restrict__ sb, us* __restrict__ node0b,
                                             const float* __restrict__ gW, us* __restrict__ Wt,
                                             const float* __restrict__ ga, us* __restrict__ VAVS,
                                             float* __restrict__ ctxz) {
    __shared__ __align__(16) float smf[8768];
    int bx = blockIdx.x, t = threadIdx.x;
    if (bx < 1024) {
        const float4* tm4 = (const float4*)tm;
        const int4* ad4 = (const int4*)adj;
        size_t base = (size_t)bx * 256 + t;
        const float C = 0.1f * LOG2E;
        const float NANF = __uint_as_float(0x7FC00000u);
        float m = -1e30f;
        #pragma unroll
        for (int k = 0; k < 8; k++) {
            size_t fi = base + (size_t)k * 262144;
            float4 v = tm4[fi];
            int4 av = ad4[fi];
            m = fmaxf(m, fmaxf(fmaxf(v.x, v.y), fmaxf(v.z, v.w)));
            float w0 = exp2f(v.x * C) * LOG2E;
            float w1 = exp2f(v.y * C) * LOG2E;
            float w2 = exp2f(v.z * C) * LOG2E;
            float w3 = exp2f(v.w * C) * LOG2E;
            w0 = av.x ? w0 : NANF;
            w1 = av.y ? w1 : NANF;
            w2 = av.z ? w2 : NANF;
            w3 = av.w ? w3 : NANF;
            uint2 pk;
            pk.x = pkh2(w0, w1);
            pk.y = pkh2(w2, w3);
            *(uint2*)&TWb[fi * 4] = pk;
        }
        smf[t] = m; __syncthreads();
        for (int s = 128; s > 0; s >>= 1) { if (t < s) smf[t] = fmaxf(smf[t], smf[t + s]); __syncthreads(); }
        if (t == 0) part[bx] = smf[0];
    } else if (bx < 1152) {
        int g = bx - 1024; int iblk = g & 15, oseg = g >> 4;
        us* As = (us*)smf;              // [64][136]
        us* Bs = (us*)smf + 64 * 136;
        const float4* esrc = (const float4*)(emb + (size_t)iblk * 64 * TD);
        const float4* wsrc = (const float4*)(sW + (size_t)oseg * 64 * TD);
        #pragma unroll
        for (int rep = 0; rep < 8; rep++) {
            int f = rep * 256 + t;
            int row = f >> 5, c4 = f & 31;
            float4 av = esrc[f];
            float4 bv = wsrc[f];
            uint2 pa, pb;
            pa.x = pkh2(av.x, av.y); pa.y = pkh2(av.z, av.w);
            pb.x = pkh2(bv.x, bv.y); pb.y = pkh2(bv.z, bv.w);
            *(uint2*)&As[row * 136 + c4 * 4] = pa;
            *(uint2*)&Bs[row * 136 + c4 * 4] = pb;
        }
        __syncthreads();
        int l = t & 63, w = t >> 6, m = l & 15, q = l >> 4;
        f32x4 acc[4];
        #pragma unroll
        for (int ot = 0; ot < 4; ot++) acc[ot] = (f32x4){0.f, 0.f, 0.f, 0.f};
        #pragma unroll
        for (int ks = 0; ks < 4; ks++) {
            half8 a = *(const half8*)&As[(w * 16 + m) * 136 + ks * 32 + q * 8];
            #pragma unroll
            for (int ot = 0; ot < 4; ot++) {
                half8 b = *(const half8*)&Bs[(ot * 16 + m) * 136 + ks * 32 + q * 8];
                acc[ot] = __builtin_amdgcn_mfma_f32_16x16x32_f16(a, b, acc[ot], 0, 0, 0);
            }
        }
        #pragma unroll
        for (int ot = 0; ot < 4; ot++) {
            int col = oseg * 64 + ot * 16 + m;
            float sbv = sb[col];
            #pragma unroll
            for (int rr = 0; rr < 4; rr++) {
                int rowi = iblk * 64 + w * 16 + q * 4 + rr;
                node0b[(size_t)rowi * HID + col] = f2h(acc[ot][rr] + sbv);
            }
        }
    } else if (bx < 1280) {
        // Wt[lh][o][k] = f16(gW[lh][k][o]); lh in [0,16), kt in [0,8)
        int g = bx - 1152; int lh = g >> 3, kt = g & 7;
        float* tile = smf;   // [64][65]
        const float4* src = (const float4*)(gW + ((size_t)lh * HID + kt * 64) * HD);
        #pragma unroll
        for (int rep = 0; rep < 4; rep++) {
            int f = rep * 256 + t;
            float4 v = src[f];
            int row = f >> 4, col = (f & 15) * 4;
            float* d = tile + row * 65 + col;
            d[0] = v.x; d[1] = v.y; d[2] = v.z; d[3] = v.w;
        }
        __syncthreads();
        int o = t >> 2, ks = (t & 3) * 16;
        us pk[16];
        #pragma unroll
        for (int j = 0; j < 16; j++) pk[j] = f2h(tile[(ks + j) * 65 + o]);
        us* dst = Wt + (size_t)lh * HD * HID + (size_t)o * HID + kt * 64 + ks;
        *(uint4*)dst = *(uint4*)pk;
        *(uint4*)(dst + 8) = *(uint4*)&pk[8];
    } else {
        // VAVS (t<128) + ctx zero-init (t>=128). 64 blocks: h = g>>3, iseg = g&7.
        int g = bx - 1280; int h = g >> 3, iseg = g & 7;
        if (t < 128) {
            int sel = t >> 6, il = t & 63;
            int i = iseg * 64 + il;
            const float* W2row = gW + (size_t)NH * HID * HD + ((size_t)h * HID + i) * HD;
            const float* a2 = ga + NH * 2 * HD + h * 2 * HD;
            const float* av = sel ? a2 : (a2 + HD);   // vs: a_src; va: a_dst
            float s = 0.f;
            #pragma unroll 8
            for (int o = 0; o < HD; o++) s = fmaf(W2row[o], av[o], s);
            VAVS[(size_t)(sel * 8 + h) * HID + i] = f2h(s);
        } else {
            int zi = (g * 128 + (t - 128)) * 4;   // covers 64*128*4 = 32768 floats (128 KB)
            *(float4*)&ctxz[zi] = make_float4(0.f, 0.f, 0.f, 0.f);
        }
    }
}

// ============ shared GEMM body (layer-1) ================================================
__device__ __forceinline__ void gemm_body(const us* __restrict__ A, const us* __restrict__ W,
                                          const float* __restrict__ gav,
                                          us* __restrict__ outT,
                                          float* __restrict__ esO, float* __restrict__ edO,
                                          int iblk, int b, int h, int t, us* sm) {
    us* As = sm;              // [2][64*72]
    us* Bs = sm + 2 * 4608;
    int row = t >> 2, ks = t & 3;
    int l = t & 63, w = t >> 6, m = l & 15, q = l >> 4;
    size_t arow0 = (size_t)(b * NT + iblk * 64);
    const us* ar = A + (arow0 + row) * HID + ks * 16;
    const us* br = W + ((size_t)(h * HD + row)) * HID + ks * 16;
    f32x4 acc[4];
    #pragma unroll
    for (int ot = 0; ot < 4; ot++) acc[ot] = (f32x4){0.f, 0.f, 0.f, 0.f};
    {
        uint4 x0 = *(const uint4*)ar, x1 = *(const uint4*)(ar + 8);
        uint4 y0 = *(const uint4*)br, y1 = *(const uint4*)(br + 8);
        *(uint4*)&As[row * 72 + ks * 16] = x0; *(uint4*)&As[row * 72 + ks * 16 + 8] = x1;
        *(uint4*)&Bs[row * 72 + ks * 16] = y0; *(uint4*)&Bs[row * 72 + ks * 16 + 8] = y1;
    }
    uint4 a0 = *(const uint4*)(ar + 64), a1 = *(const uint4*)(ar + 72);
    uint4 b0 = *(const uint4*)(br + 64), b1 = *(const uint4*)(br + 72);
    for (int it = 0; it < 8; it++) {
        int cur = it & 1, nxt = cur ^ 1;
        uint4 na0, na1, nb0, nb1;
        if (it < 6) {
            int k0 = (it + 2) * 64;
            na0 = *(const uint4*)(ar + k0); na1 = *(const uint4*)(ar + k0 + 8);
            nb0 = *(const uint4*)(br + k0); nb1 = *(const uint4*)(br + k0 + 8);
        }
        __syncthreads();
        if (it < 7) {
            *(uint4*)&As[nxt * 4608 + row * 72 + ks * 16] = a0;
            *(uint4*)&As[nxt * 4608 + row * 72 + ks * 16 + 8] = a1;
            *(uint4*)&Bs[nxt * 4608 + row * 72 + ks * 16] = b0;
            *(uint4*)&Bs[nxt * 4608 + row * 72 + ks * 16 + 8] = b1;
        }
        const us* Ac = As + cur * 4608; const us* Bc = Bs + cur * 4608;
        #pragma unroll
        for (int kt = 0; kt < 2; kt++) {
            half8 av = *(const half8*)&Ac[(w * 16 + m) * 72 + kt * 32 + q * 8];
            #pragma unroll
            for (int ot = 0; ot < 4; ot++) {
                half8 bv = *(const half8*)&Bc[(ot * 16 + m) * 72 + kt * 32 + q * 8];
                acc[ot] = __builtin_amdgcn_mfma_f32_16x16x32_f16(av, bv, acc[ot], 0, 0, 0);
            }
        }
        if (it < 6) { a0 = na0; a1 = na1; b0 = nb0; b1 = nb1; }
    }
    const float* gas = gav + h * 2 * HD;
    float gs[4], gd[4];
    #pragma unroll
    for (int ot = 0; ot < 4; ot++) { gs[ot] = gas[ot * 16 + m]; gd[ot] = gas[HD + ot * 16 + m]; }
    size_t ebase = ((size_t)b * NH + h) * NT + iblk * 64;
    #pragma unroll
    for (int rr = 0; rr < 4; rr++) {
        float s = 0.f, d = 0.f;
        #pragma unroll
        for (int ot = 0; ot < 4; ot++) { float v = acc[ot][rr]; s = fmaf(v, gs[ot], s); d = fmaf(v, gd[ot], d); }
        #pragma unroll
        for (int mask = 1; mask < 16; mask <<= 1) { s += __shfl_xor(s, mask); d += __shfl_xor(d, mask); }
        if (m == 0) {
            int rowi = w * 16 + q * 4 + rr;
            esO[ebase + rowi] = s;
            edO[ebase + rowi] = d;
        }
    }
    #pragma unroll
    for (int ot = 0; ot < 4; ot++) {
        int col = h * HD + ot * 16 + m;
        #pragma unroll
        for (int rr = 0; rr < 4; rr++) {
            int i_loc = w * 16 + q * 4 + rr;
            outT[(size_t)col * NT + iblk * 64 + i_loc] = f2h(acc[ot][rr]);
        }
    }
}

// ============ layer-1 GEMM (128 blocks) ================================================
__global__ __launch_bounds__(256) void kgemm1(const us* __restrict__ node0b, const us* __restrict__ Wt,
                                              const float* __restrict__ ga, us* __restrict__ Ht1,
                                              float* __restrict__ es1, float* __restrict__ ed1) {
    __shared__ __align__(16) us sm[4 * 4608];
    int g = blockIdx.x;
    gemm_body(node0b, Wt, ga, Ht1, es1, ed1, g & 15, 0, g >> 4, threadIdx.x, sm);
}

// ============ layer-1 attention ========================================================
__device__ __forceinline__ unsigned int p_word_fly(unsigned int tw, unsigned int ed, h16x2 es) {
    h16x2 t = __builtin_bit_cast(h16x2, tw);
    h16x2 d = __builtin_bit_cast(h16x2, ed);
    h16x2 e = es + d;
    h16x2 lk = e * (h16)0.2f;
    h16x2 el = __builtin_elementwise_max(e, lk);
    h16x2 mm = t * el;
    h16x2 p;
    p.x = __ocml_exp2_f16(mm.x);
    p.y = __ocml_exp2_f16(mm.y);
    h16x2 z = {(h16)0.0f, (h16)0.0f};
    h16x2 r = __builtin_elementwise_max(p, z);
    return __builtin_bit_cast(unsigned int, r);
}

__device__ __forceinline__ half8 p_frag(uint4 T, uint4 D, h16x2 es) {
    uint4 r;
    r.x = p_word_fly(T.x, D.x, es);
    r.y = p_word_fly(T.y, D.y, es);
    r.z = p_word_fly(T.z, D.z, es);
    r.w = p_word_fly(T.w, D.w, es);
    return __builtin_bit_cast(half8, r);
}

__global__ __launch_bounds__(256) void kattn1(const us* __restrict__ TWb, const us* __restrict__ Ht,
                                              const float* __restrict__ es1, const float* __restrict__ ed1,
                                              const float* __restrict__ part, us* __restrict__ node1b) {
    int n = blockIdx.x;               // 512 blocks; b=n&7 -> one batch per XCD
    int b = n & 7, k = n >> 3;
    int i2 = k & 7, h = k >> 3;
    int t = threadIdx.x;
    __shared__ __align__(16) us Hs[2][64 * 72];
    __shared__ __align__(16) us edl[NT];
    __shared__ float invl_s[128];
    __shared__ float reds[256];
    int l = t & 63, w = t >> 6, m = l & 15, q = l >> 4;
    {
        float pm = fmaxf(fmaxf(part[t * 4], part[t * 4 + 1]), fmaxf(part[t * 4 + 2], part[t * 4 + 3]));
        reds[t] = pm; __syncthreads();
        for (int s = 128; s > 0; s >>= 1) { if (t < s) reds[t] = fmaxf(reds[t], reds[t + s]); __syncthreads(); }
    }
    float sfac = exp2f(-reds[0] * (0.1f * LOG2E));
    {
        float4 ev = *(const float4*)&ed1[h * NT + t * 4];
        uint2 pk; pk.x = pkh2(ev.x * sfac, ev.y * sfac); pk.y = pkh2(ev.z * sfac, ev.w * sfac);
        *(uint2*)&edl[t * 4] = pk;
    }
    int rowA = i2 * 128 + w * 32 + m;
    h16 eA = (h16)(es1[h * NT + rowA] * sfac);
    h16 eB = (h16)(es1[h * NT + rowA + 16] * sfac);
    h16x2 esvA = {eA, eA}, esvB = {eB, eB};
    const us* twA = TWb + ((size_t)(b * NT) + rowA) * NT + q * 8;
    const us* twB = twA + (size_t)16 * NT;
    int hr = t >> 2, js = t & 3;
    const us* htrow = Ht + ((size_t)(h * HD) + hr) * NT + js * 16;
    f32x4 acc[2][4];
    #pragma unroll
    for (int ti = 0; ti < 2; ti++)
        #pragma unroll
        for (int ot = 0; ot < 4; ot++) acc[ti][ot] = (f32x4){0.f, 0.f, 0.f, 0.f};
    f32x4 acc1[2] = {(f32x4){0.f, 0.f, 0.f, 0.f}, (f32x4){0.f, 0.f, 0.f, 0.f}};
    h16 ov = (m == 0) ? (h16)1.0f : (h16)0.0f;
    half8 bones = {ov, ov, ov, ov, ov, ov, ov, ov};
    uint4 H0 = *(const uint4*)htrow, H1 = *(const uint4*)(htrow + 8);
    *(uint4*)&Hs[0][hr * 72 + js * 16] = H0;
    *(uint4*)&Hs[0][hr * 72 + js * 16 + 8] = H1;
    H0 = *(const uint4*)(htrow + 64); H1 = *(const uint4*)(htrow + 72);
    uint4 TA0 = *(const uint4*)twA,        TA1 = *(const uint4*)(twA + 32);
    uint4 TB0 = *(const uint4*)twB,        TB1 = *(const uint4*)(twB + 32);
    __syncthreads();
    for (int it = 0; it < 16; it++) {
        int cur = it & 1, nxt = cur ^ 1;
        int j0 = it * 64;
        uint4 nH0, nH1, nA0, nA1, nB0, nB1;
        if (it < 14) {
            nH0 = *(const uint4*)(htrow + j0 + 128);
            nH1 = *(const uint4*)(htrow + j0 + 136);
        }
        if (it < 15) {
            nA0 = *(const uint4*)(twA + j0 + 64);  nA1 = *(const uint4*)(twA + j0 + 96);
            nB0 = *(const uint4*)(twB + j0 + 64);  nB1 = *(const uint4*)(twB + j0 + 96);
        }
        uint4 D0 = *(const uint4*)&edl[j0 + q * 8];
        uint4 D1 = *(const uint4*)&edl[j0 + 32 + q * 8];
        half8 pA0 = p_frag(TA0, D0, esvA);
        half8 pA1 = p_frag(TA1, D1, esvA);
        half8 pB0 = p_frag(TB0, D0, esvB);
        half8 pB1 = p_frag(TB1, D1, esvB);
        __syncthreads();
        if (it < 15) {
            *(uint4*)&Hs[nxt][hr * 72 + js * 16] = H0;
            *(uint4*)&Hs[nxt][hr * 72 + js * 16 + 8] = H1;
        }
        const us* Hc = Hs[cur];
        #pragma unroll
        for (int ot = 0; ot < 4; ot++) {
            half8 bv0 = *(const half8*)&Hc[(ot * 16 + m) * 72 + q * 8];
            half8 bv1 = *(const half8*)&Hc[(ot * 16 + m) * 72 + 32 + q * 8];
            acc[0][ot] = __builtin_amdgcn_mfma_f32_16x16x32_f16(pA0, bv0, acc[0][ot], 0, 0, 0);
            acc[0][ot] = __builtin_amdgcn_mfma_f32_16x16x32_f16(pA1, bv1, acc[0][ot], 0, 0, 0);
            acc[1][ot] = __builtin_amdgcn_mfma_f32_16x16x32_f16(pB0, bv0, acc[1][ot], 0, 0, 0);
            acc[1][ot] = __builtin_amdgcn_mfma_f32_16x16x32_f16(pB1, bv1, acc[1][ot], 0, 0, 0);
        }
        acc1[0] = __builtin_amdgcn_mfma_f32_16x16x32_f16(pA0, bones, acc1[0], 0, 0, 0);
        acc1[0] = __builtin_amdgcn_mfma_f32_16x16x32_f16(pA1, bones, acc1[0], 0, 0, 0);
        acc1[1] = __builtin_amdgcn_mfma_f32_16x16x32_f16(pB0, bones, acc1[1], 0, 0, 0);
        acc1[1] = __builtin_amdgcn_mfma_f32_16x16x32_f16(pB1, bones, acc1[1], 0, 0, 0);
        if (it < 14) { H0 = nH0; H1 = nH1; }
        if (it < 15) { TA0 = nA0; TA1 = nA1; TB0 = nB0; TB1 = nB1; }
    }
    if (m == 0) {
        #pragma unroll
        for (int rr = 0; rr < 4; rr++) {
            invl_s[w * 32 + q * 4 + rr]      = 1.f / acc1[0][rr];
            invl_s[w * 32 + 16 + q * 4 + rr] = 1.f / acc1[1][rr];
        }
    }
    __syncthreads();
    size_t rbase = (size_t)(b * NT + i2 * 128);
    #pragma unroll
    for (int ti = 0; ti < 2; ti++) {
        #pragma unroll
        for (int ot = 0; ot < 4; ot++) {
            int col = h * HD + ot * 16 + m;
            #pragma unroll
            for (int rr = 0; rr < 4; rr++) {
                int rloc = w * 32 + ti * 16 + q * 4 + rr;
                float v = acc[ti][ot][rr] * invl_s[rloc];
                v = v > 0.f ? v : (__expf(v) - 1.f);
                node1b[(rbase + rloc) * HID + col] = f2h(v);
            }
        }
    }
}

// ============ kctx: layer-2 attention via PV associativity; atomic ctx accumulate ======
__global__ __launch_bounds__(256) void kctx(const us* __restrict__ TWb, const us* __restrict__ node1b,
                                            const us* __restrict__ VAVS, const float* __restrict__ part,
                                            const int* __restrict__ topic_ids,
                                            float* __restrict__ ctx, float* __restrict__ pl) {
    int n = blockIdx.x;          // 256: b = n&7, jb = n>>3 (32 rows each)
    int b = n & 7, jb = n >> 3;
    int t = threadIdx.x;
    __shared__ __align__(16) us n1s[32 * 520];
    __shared__ __align__(16) us vvs[16 * 520];
    __shared__ __align__(16) us qrow[HID];
    __shared__ float Ps[8][33];
    __shared__ float es2q[8];
    __shared__ float reds[256];
    int qi = topic_ids[b];
    {
        float pm = fmaxf(fmaxf(part[t * 4], part[t * 4 + 1]), fmaxf(part[t * 4 + 2], part[t * 4 + 3]));
        reds[t] = pm; __syncthreads();
        for (int s = 128; s > 0; s >>= 1) { if (t < s) reds[t] = fmaxf(reds[t], reds[t + s]); __syncthreads(); }
    }
    float sfac = exp2f(-reds[0] * (0.1f * LOG2E));
    {   // stage node1 tile [32][512]
        int row = t >> 3, c = (t & 7) * 64;
        const uint4* src = (const uint4*)(node1b + ((size_t)(b * NT) + jb * 32 + row) * HID + c);
        uint4* dst = (uint4*)&n1s[row * 520 + c];
        #pragma unroll
        for (int k = 0; k < 8; k++) dst[k] = src[k];
    }
    {   // stage VAVS [16][512]
        int row = t >> 4, c = (t & 15) * 32;
        const uint4* src = (const uint4*)(VAVS + (size_t)row * HID + c);
        uint4* dst = (uint4*)&vvs[row * 520 + c];
        dst[0] = src[0]; dst[1] = src[1]; dst[2] = src[2]; dst[3] = src[3];
    }
    if (t < 32) {   // stage node1 row qi
        const uint4* src = (const uint4*)(node1b + ((size_t)(b * NT) + qi) * HID + t * 16);
        *(uint4*)&qrow[t * 16] = src[0];
        *(uint4*)&qrow[t * 16 + 8] = src[1];
    }
    __syncthreads();
    {   // es2q[h] = sum_i qrow[i]*vs[h][i]
        int h = t >> 5, li = t & 31;
        float s = 0.f;
        #pragma unroll 4
        for (int ii = 0; ii < 16; ii++) {
            int i = li * 16 + ii;
            s = fmaf(h2f(qrow[i]), h2f(vvs[(8 + h) * 520 + i]), s);
        }
        #pragma unroll
        for (int mask = 1; mask < 32; mask <<= 1) s += __shfl_xor(s, mask);
        if (li == 0) es2q[h] = s;
    }
    __syncthreads();
    int l = t & 63, w = t >> 6, m = l & 15, q = l >> 4;
    if (w < 2) {   // ed via MFMA: [32 j] x [16 n], K=512
        f32x4 acc = (f32x4){0.f, 0.f, 0.f, 0.f};
        #pragma unroll
        for (int kt = 0; kt < 16; kt++) {
            half8 a = *(const half8*)&n1s[(w * 16 + m) * 520 + kt * 32 + q * 8];
            half8 bv = *(const half8*)&vvs[m * 520 + kt * 32 + q * 8];
            acc = __builtin_amdgcn_mfma_f32_16x16x32_f16(a, bv, acc, 0, 0, 0);
        }
        if (m < 8) {   // P[h=m][j]
            const us* twq = TWb + ((size_t)(b * NT) + qi) * NT + jb * 32;
            float esv = es2q[m];
            #pragma unroll
            for (int r = 0; r < 4; r++) {
                int j = w * 16 + q * 4 + r;
                float e = esv + acc[r];
                e = fmaxf(e, 0.2f * e);
                float twu = h2f(twq[j]);
                float p = fmaxf(exp2f(twu * sfac * e), 0.f);   // NaN -> 0
                Ps[m][j] = p;
            }
        }
    }
    __syncthreads();
    {   // pl[b][h][jb]
        int h = t >> 5, j = t & 31;
        float s = Ps[h][j];
        #pragma unroll
        for (int mask = 1; mask < 32; mask <<= 1) s += __shfl_xor(s, mask);
        if (j == 0) pl[((size_t)b * NH + h) * 32 + jb] = s;
    }
    // partial ctx: thread owns o pair (t*2, t*2+1); accumulate via device atomics
    float ac[8][2];
    #pragma unroll
    for (int h = 0; h < 8; h++) { ac[h][0] = 0.f; ac[h][1] = 0.f; }
    for (int j = 0; j < 32; j++) {
        unsigned int uv = *(const unsigned int*)&n1s[j * 520 + t * 2];
        h16x2 hv = __builtin_bit_cast(h16x2, uv);
        float f0 = (float)hv.x, f1 = (float)hv.y;
        #pragma unroll
        for (int h = 0; h < 8; h++) {
            float p = Ps[h][j];
            ac[h][0] = fmaf(p, f0, ac[h][0]);
            ac[h][1] = fmaf(p, f1, ac[h][1]);
        }
    }
    float* cp = ctx + ((size_t)b * NH) * HID;
    #pragma unroll
    for (int h = 0; h < 8; h++) {
        atomicAdd(&cp[h * HID + t * 2], ac[h][0]);
        atomicAdd(&cp[h * HID + t * 2 + 1], ac[h][1]);
    }
}

// ============ kout: normalize ctx, @W2, ELU, +attract, fc1+relu+fc2 -> out[b] ==========
__global__ __launch_bounds__(256) void kout(const float* __restrict__ ctx, const float* __restrict__ pl,
                                            const us* __restrict__ Wt2, const float* __restrict__ attr,
                                            const float* __restrict__ aW, const float* __restrict__ ab,
                                            const float* __restrict__ fc1W, const float* __restrict__ fc1b,
                                            const float* __restrict__ fc2W, const float* __restrict__ fc2b,
                                            float* __restrict__ out) {
    int b = blockIdx.x;
    int t = threadIdx.x;
    __shared__ float cxs[NH * HID];   // 16 KB
    __shared__ float comb[HID];
    __shared__ float linv[NH];
    __shared__ float r2[256];
    {
        int h = t >> 5, j = t & 31;
        float s = pl[((size_t)b * NH + h) * 32 + j];
        #pragma unroll
        for (int mask = 1; mask < 32; mask <<= 1) s += __shfl_xor(s, mask);
        if (j == 0) linv[h] = 1.f / s;
    }
    __syncthreads();
    #pragma unroll
    for (int rep = 0; rep < 16; rep++) {
        int i = rep * 256 + t;
        cxs[i] = ctx[(size_t)b * NH * HID + i] * linv[i >> 9];
    }
    __syncthreads();
    #pragma unroll
    for (int cc = 0; cc < 2; cc++) {
        int col = cc * 256 + t;          // col = h*64 + o2
        int h = col >> 6;
        const us* wrow = Wt2 + (size_t)col * HID;
        const float* cx = &cxs[h * HID];
        float s = 0.f;
        #pragma unroll 8
        for (int k = 0; k < HID; k++) s = fmaf(cx[k], h2f(wrow[k]), s);
        float v = s > 0.f ? s : (__expf(s) - 1.f);   // ELU
        comb[col] = v + attr[b] * aW[col] + ab[col];
    }
    __syncthreads();
    float partv = 0.f;
    int j = t & 15;
    for (int g = 0; g < 32; g++) {
        int kk = g * 16 + (t >> 4);
        const float* row = fc1W + (size_t)kk * HID;
        float acc = 0.f;
        #pragma unroll 8
        for (int mi = 0; mi < 32; mi++) {
            int idx = mi * 16 + j;
            acc = fmaf(comb[idx], row[idx], acc);
        }
        #pragma unroll
        for (int mask = 1; mask < 16; mask <<= 1) acc += __shfl_xor(acc, mask);
        if (j == 0) {
            float hk = fmaxf(acc + fc1b[kk], 0.f);
            partv = fmaf(hk, fc2W[kk], partv);
        }
    }
    r2[t] = partv; __syncthreads();
    for (int s = 128; s > 0; s >>= 1) { if (t < s) r2[t] += r2[t + s]; __syncthreads(); }
    if (t == 0) out[b] = r2[0] + fc2b[0];
}

extern "C" void kernel_launch(void* const* d_in, const int* in_sizes, int n_in,
                              void* d_out, int out_size, void* d_ws, size_t ws_size,
                              hipStream_t stream) {
    const int*   topic_ids = (const int*)d_in[0];
    const int*   adj       = (const int*)d_in[1];
    const float* tm        = (const float*)d_in[2];
    const float* attr      = (const float*)d_in[3];
    const float* emb       = (const float*)d_in[4];
    const float* sW        = (const float*)d_in[5];
    const float* sb        = (const float*)d_in[6];
    const float* aW        = (const float*)d_in[7];
    const float* ab        = (const float*)d_in[8];
    const float* gW        = (const float*)d_in[9];   // (2,8,512,64)
    const float* ga        = (const float*)d_in[10];  // (2,8,128,1)
    const float* fc1W      = (const float*)d_in[11];
    const float* fc1b      = (const float*)d_in[12];
    const float* fc2W      = (const float*)d_in[13];
    const float* fc2b      = (const float*)d_in[14];
    float* out = (float*)d_out;

    char* p = (char*)d_ws;
    us* TWb    = (us*)p; p += sizeof(us) * (size_t)NB * NT * NT;        // 16.8 MB
    us* node0b = (us*)p; p += sizeof(us) * (size_t)NT * HID;            // 1 MB
    us* Wt     = (us*)p; p += sizeof(us) * (size_t)2 * NH * HD * HID;   // 1 MB
    us* Ht1    = (us*)p; p += sizeof(us) * (size_t)HID * NT;            // 1 MB
    us* node1b = (us*)p; p += sizeof(us) * (size_t)NB * NT * HID;       // 8 MB
    us* VAVS   = (us*)p; p += sizeof(us) * (size_t)16 * HID;            // 16 KB
    float* es1  = (float*)p; p += sizeof(float) * NH * NT;
    float* ed1  = (float*)p; p += sizeof(float) * NH * NT;
    float* ctx  = (float*)p; p += sizeof(float) * (size_t)NB * NH * HID;  // 128 KB
    float* pl   = (float*)p; p += sizeof(float) * NB * NH * 32;
    float* part = (float*)p; p += sizeof(float) * 1024;

    kprep<<<1344, 256, 0, stream>>>(tm, adj, part, TWb, emb, sW, sb, node0b, gW, Wt, ga, VAVS, ctx);
    kgemm1<<<128, 256, 0, stream>>>(node0b, Wt, ga, Ht1, es1, ed1);
    kattn1<<<512, 256, 0, stream>>>(TWb, Ht1, es1, ed1, part, node1b);
    kctx<<<256, 256, 0, stream>>>(TWb, node1b, VAVS, part, topic_ids, ctx, pl);
    kout<<<8, 256, 0, stream>>>(ctx, pl, Wt + (size_t)NH * HD * HID, attr, aW, ab,
                                fc1W, fc1b, fc2W, fc2b, out);
}

// Round 10
// 181.442 us; speedup vs baseline: 1.3767x; 1.3767x over previous
//
#include <hip/hip_runtime.h>

#define NT 1024      // N_TOPICS
#define TD 128       // TOPIC_DIM
#define HID 512      // HIDDEN
#define NH 8         // N_HEADS
#define HD 64        // HEAD_DIM
#define NB 8         // BATCH

typedef unsigned short us;
typedef _Float16 h16;
typedef h16 half8 __attribute__((ext_vector_type(8)));
typedef h16 h16x2 __attribute__((ext_vector_type(2)));
typedef float f32x4 __attribute__((ext_vector_type(4)));

#define LOG2E 1.44269504f

extern "C" __device__ _Float16 __ocml_exp2_f16(_Float16);

__device__ __forceinline__ us f2h(float x) { return __builtin_bit_cast(us, (h16)x); }
__device__ __forceinline__ float h2f(us s) { return (float)__builtin_bit_cast(h16, s); }
__device__ __forceinline__ unsigned int pkh2(float a, float b) {
    auto v = __builtin_amdgcn_cvt_pkrtz(a, b);
    return __builtin_bit_cast(unsigned int, v);
}

// ============ kprep: fused max-scan + TWu (0-1023) | node0 GEMM (1024-1151)
//              | gW transpose (1152-1279; block 1152 inits out) | VAVS + ctx-zero (1280-1343)
__global__ __launch_bounds__(256) void kprep(const float* __restrict__ tm, const int* __restrict__ adj,
                                             float* __restrict__ part, us* __restrict__ TWb,
                                             const float* __restrict__ emb, const float* __restrict__ sW,
                                             const float* __restrict__ sb, us* __restrict__ node0b,
                                             const float* __restrict__ gW, us* __restrict__ Wt,
                                             const float* __restrict__ ga, us* __restrict__ VAVS,
                                             float* __restrict__ ctxz,
                                             const float* __restrict__ fc2b, float* __restrict__ out) {
    __shared__ __align__(16) float smf[8768];
    int bx = blockIdx.x, t = threadIdx.x;
    if (bx < 1024) {
        const float4* tm4 = (const float4*)tm;
        const int4* ad4 = (const int4*)adj;
        size_t base = (size_t)bx * 256 + t;
        const float C = 0.1f * LOG2E;
        const float NANF = __uint_as_float(0x7FC00000u);
        float m = -1e30f;
        #pragma unroll
        for (int k = 0; k < 8; k++) {
            size_t fi = base + (size_t)k * 262144;
            float4 v = tm4[fi];
            int4 av = ad4[fi];
            m = fmaxf(m, fmaxf(fmaxf(v.x, v.y), fmaxf(v.z, v.w)));
            float w0 = exp2f(v.x * C) * LOG2E;
            float w1 = exp2f(v.y * C) * LOG2E;
            float w2 = exp2f(v.z * C) * LOG2E;
            float w3 = exp2f(v.w * C) * LOG2E;
            w0 = av.x ? w0 : NANF;
            w1 = av.y ? w1 : NANF;
            w2 = av.z ? w2 : NANF;
            w3 = av.w ? w3 : NANF;
            uint2 pk;
            pk.x = pkh2(w0, w1);
            pk.y = pkh2(w2, w3);
            *(uint2*)&TWb[fi * 4] = pk;
        }
        smf[t] = m; __syncthreads();
        for (int s = 128; s > 0; s >>= 1) { if (t < s) smf[t] = fmaxf(smf[t], smf[t + s]); __syncthreads(); }
        if (t == 0) part[bx] = smf[0];
    } else if (bx < 1152) {
        int g = bx - 1024; int iblk = g & 15, oseg = g >> 4;
        us* As = (us*)smf;              // [64][136]
        us* Bs = (us*)smf + 64 * 136;
        const float4* esrc = (const float4*)(emb + (size_t)iblk * 64 * TD);
        const float4* wsrc = (const float4*)(sW + (size_t)oseg * 64 * TD);
        #pragma unroll
        for (int rep = 0; rep < 8; rep++) {
            int f = rep * 256 + t;
            int row = f >> 5, c4 = f & 31;
            float4 av = esrc[f];
            float4 bv = wsrc[f];
            uint2 pa, pb;
            pa.x = pkh2(av.x, av.y); pa.y = pkh2(av.z, av.w);
            pb.x = pkh2(bv.x, bv.y); pb.y = pkh2(bv.z, bv.w);
            *(uint2*)&As[row * 136 + c4 * 4] = pa;
            *(uint2*)&Bs[row * 136 + c4 * 4] = pb;
        }
        __syncthreads();
        int l = t & 63, w = t >> 6, m = l & 15, q = l >> 4;
        f32x4 acc[4];
        #pragma unroll
        for (int ot = 0; ot < 4; ot++) acc[ot] = (f32x4){0.f, 0.f, 0.f, 0.f};
        #pragma unroll
        for (int ks = 0; ks < 4; ks++) {
            half8 a = *(const half8*)&As[(w * 16 + m) * 136 + ks * 32 + q * 8];
            #pragma unroll
            for (int ot = 0; ot < 4; ot++) {
                half8 b = *(const half8*)&Bs[(ot * 16 + m) * 136 + ks * 32 + q * 8];
                acc[ot] = __builtin_amdgcn_mfma_f32_16x16x32_f16(a, b, acc[ot], 0, 0, 0);
            }
        }
        #pragma unroll
        for (int ot = 0; ot < 4; ot++) {
            int col = oseg * 64 + ot * 16 + m;
            float sbv = sb[col];
            #pragma unroll
            for (int rr = 0; rr < 4; rr++) {
                int rowi = iblk * 64 + w * 16 + q * 4 + rr;
                node0b[(size_t)rowi * HID + col] = f2h(acc[ot][rr] + sbv);
            }
        }
    } else if (bx < 1280) {
        // Wt[lh][o][k] = f16(gW[lh][k][o]); lh in [0,16), kt in [0,8)
        int g = bx - 1152; int lh = g >> 3, kt = g & 7;
        if (g == 0 && t < NB) out[t] = fc2b[0];   // init for kfc atomics
        float* tile = smf;   // [64][65]
        const float4* src = (const float4*)(gW + ((size_t)lh * HID + kt * 64) * HD);
        #pragma unroll
        for (int rep = 0; rep < 4; rep++) {
            int f = rep * 256 + t;
            float4 v = src[f];
            int row = f >> 4, col = (f & 15) * 4;
            float* d = tile + row * 65 + col;
            d[0] = v.x; d[1] = v.y; d[2] = v.z; d[3] = v.w;
        }
        __syncthreads();
        int o = t >> 2, ks = (t & 3) * 16;
        us pk[16];
        #pragma unroll
        for (int j = 0; j < 16; j++) pk[j] = f2h(tile[(ks + j) * 65 + o]);
        us* dst = Wt + (size_t)lh * HD * HID + (size_t)o * HID + kt * 64 + ks;
        *(uint4*)dst = *(uint4*)pk;
        *(uint4*)(dst + 8) = *(uint4*)&pk[8];
    } else {
        // VAVS (t<128) + ctx zero-init (t>=128). 64 blocks: h = g>>3, iseg = g&7.
        int g = bx - 1280; int h = g >> 3, iseg = g & 7;
        if (t < 128) {
            int sel = t >> 6, il = t & 63;
            int i = iseg * 64 + il;
            const float* W2row = gW + (size_t)NH * HID * HD + ((size_t)h * HID + i) * HD;
            const float* a2 = ga + NH * 2 * HD + h * 2 * HD;
            const float* av = sel ? a2 : (a2 + HD);   // vs: a_src; va: a_dst
            float s = 0.f;
            #pragma unroll 8
            for (int o = 0; o < HD; o++) s = fmaf(W2row[o], av[o], s);
            VAVS[(size_t)(sel * 8 + h) * HID + i] = f2h(s);
        } else {
            int zi = (g * 128 + (t - 128)) * 4;   // 64*128*4 = 32768 floats (128 KB)
            *(float4*)&ctxz[zi] = make_float4(0.f, 0.f, 0.f, 0.f);
        }
    }
}

// ============ shared GEMM body (layer-1) ================================================
__device__ __forceinline__ void gemm_body(const us* __restrict__ A, const us* __restrict__ W,
                                          const float* __restrict__ gav,
                                          us* __restrict__ outT,
                                          float* __restrict__ esO, float* __restrict__ edO,
                                          int iblk, int b, int h, int t, us* sm) {
    us* As = sm;              // [2][64*72]
    us* Bs = sm + 2 * 4608;
    int row = t >> 2, ks = t & 3;
    int l = t & 63, w = t >> 6, m = l & 15, q = l >> 4;
    size_t arow0 = (size_t)(b * NT + iblk * 64);
    const us* ar = A + (arow0 + row) * HID + ks * 16;
    const us* br = W + ((size_t)(h * HD + row)) * HID + ks * 16;
    f32x4 acc[4];
    #pragma unroll
    for (int ot = 0; ot < 4; ot++) acc[ot] = (f32x4){0.f, 0.f, 0.f, 0.f};
    {
        uint4 x0 = *(const uint4*)ar, x1 = *(const uint4*)(ar + 8);
        uint4 y0 = *(const uint4*)br, y1 = *(const uint4*)(br + 8);
        *(uint4*)&As[row * 72 + ks * 16] = x0; *(uint4*)&As[row * 72 + ks * 16 + 8] = x1;
        *(uint4*)&Bs[row * 72 + ks * 16] = y0; *(uint4*)&Bs[row * 72 + ks * 16 + 8] = y1;
    }
    uint4 a0 = *(const uint4*)(ar + 64), a1 = *(const uint4*)(ar + 72);
    uint4 b0 = *(const uint4*)(br + 64), b1 = *(const uint4*)(br + 72);
    for (int it = 0; it < 8; it++) {
        int cur = it & 1, nxt = cur ^ 1;
        uint4 na0, na1, nb0, nb1;
        if (it < 6) {
            int k0 = (it + 2) * 64;
            na0 = *(const uint4*)(ar + k0); na1 = *(const uint4*)(ar + k0 + 8);
            nb0 = *(const uint4*)(br + k0); nb1 = *(const uint4*)(br + k0 + 8);
        }
        __syncthreads();
        if (it < 7) {
            *(uint4*)&As[nxt * 4608 + row * 72 + ks * 16] = a0;
            *(uint4*)&As[nxt * 4608 + row * 72 + ks * 16 + 8] = a1;
            *(uint4*)&Bs[nxt * 4608 + row * 72 + ks * 16] = b0;
            *(uint4*)&Bs[nxt * 4608 + row * 72 + ks * 16 + 8] = b1;
        }
        const us* Ac = As + cur * 4608; const us* Bc = Bs + cur * 4608;
        #pragma unroll
        for (int kt = 0; kt < 2; kt++) {
            half8 av = *(const half8*)&Ac[(w * 16 + m) * 72 + kt * 32 + q * 8];
            #pragma unroll
            for (int ot = 0; ot < 4; ot++) {
                half8 bv = *(const half8*)&Bc[(ot * 16 + m) * 72 + kt * 32 + q * 8];
                acc[ot] = __builtin_amdgcn_mfma_f32_16x16x32_f16(av, bv, acc[ot], 0, 0, 0);
            }
        }
        if (it < 6) { a0 = na0; a1 = na1; b0 = nb0; b1 = nb1; }
    }
    const float* gas = gav + h * 2 * HD;
    float gs[4], gd[4];
    #pragma unroll
    for (int ot = 0; ot < 4; ot++) { gs[ot] = gas[ot * 16 + m]; gd[ot] = gas[HD + ot * 16 + m]; }
    size_t ebase = ((size_t)b * NH + h) * NT + iblk * 64;
    #pragma unroll
    for (int rr = 0; rr < 4; rr++) {
        float s = 0.f, d = 0.f;
        #pragma unroll
        for (int ot = 0; ot < 4; ot++) { float v = acc[ot][rr]; s = fmaf(v, gs[ot], s); d = fmaf(v, gd[ot], d); }
        #pragma unroll
        for (int mask = 1; mask < 16; mask <<= 1) { s += __shfl_xor(s, mask); d += __shfl_xor(d, mask); }
        if (m == 0) {
            int rowi = w * 16 + q * 4 + rr;
            esO[ebase + rowi] = s;
            edO[ebase + rowi] = d;
        }
    }
    #pragma unroll
    for (int ot = 0; ot < 4; ot++) {
        int col = h * HD + ot * 16 + m;
        #pragma unroll
        for (int rr = 0; rr < 4; rr++) {
            int i_loc = w * 16 + q * 4 + rr;
            outT[(size_t)col * NT + iblk * 64 + i_loc] = f2h(acc[ot][rr]);
        }
    }
}

// ============ layer-1 GEMM (128 blocks) ================================================
__global__ __launch_bounds__(256) void kgemm1(const us* __restrict__ node0b, const us* __restrict__ Wt,
                                              const float* __restrict__ ga, us* __restrict__ Ht1,
                                              float* __restrict__ es1, float* __restrict__ ed1) {
    __shared__ __align__(16) us sm[4 * 4608];
    int g = blockIdx.x;
    gemm_body(node0b, Wt, ga, Ht1, es1, ed1, g & 15, 0, g >> 4, threadIdx.x, sm);
}

// ============ layer-1 attention ========================================================
__device__ __forceinline__ unsigned int p_word_fly(unsigned int tw, unsigned int ed, h16x2 es) {
    h16x2 t = __builtin_bit_cast(h16x2, tw);
    h16x2 d = __builtin_bit_cast(h16x2, ed);
    h16x2 e = es + d;
    h16x2 lk = e * (h16)0.2f;
    h16x2 el = __builtin_elementwise_max(e, lk);
    h16x2 mm = t * el;
    h16x2 p;
    p.x = __ocml_exp2_f16(mm.x);
    p.y = __ocml_exp2_f16(mm.y);
    h16x2 z = {(h16)0.0f, (h16)0.0f};
    h16x2 r = __builtin_elementwise_max(p, z);
    return __builtin_bit_cast(unsigned int, r);
}

__device__ __forceinline__ half8 p_frag(uint4 T, uint4 D, h16x2 es) {
    uint4 r;
    r.x = p_word_fly(T.x, D.x, es);
    r.y = p_word_fly(T.y, D.y, es);
    r.z = p_word_fly(T.z, D.z, es);
    r.w = p_word_fly(T.w, D.w, es);
    return __builtin_bit_cast(half8, r);
}

__global__ __launch_bounds__(256) void kattn1(const us* __restrict__ TWb, const us* __restrict__ Ht,
                                              const float* __restrict__ es1, const float* __restrict__ ed1,
                                              const float* __restrict__ part, us* __restrict__ node1b) {
    int n = blockIdx.x;               // 512 blocks; b=n&7 -> one batch per XCD
    int b = n & 7, k = n >> 3;
    int i2 = k & 7, h = k >> 3;
    int t = threadIdx.x;
    __shared__ __align__(16) us Hs[2][64 * 72];
    __shared__ __align__(16) us edl[NT];
    __shared__ float invl_s[128];
    __shared__ float reds[256];
    int l = t & 63, w = t >> 6, m = l & 15, q = l >> 4;
    {
        float pm = fmaxf(fmaxf(part[t * 4], part[t * 4 + 1]), fmaxf(part[t * 4 + 2], part[t * 4 + 3]));
        reds[t] = pm; __syncthreads();
        for (int s = 128; s > 0; s >>= 1) { if (t < s) reds[t] = fmaxf(reds[t], reds[t + s]); __syncthreads(); }
    }
    float sfac = exp2f(-reds[0] * (0.1f * LOG2E));
    {
        float4 ev = *(const float4*)&ed1[h * NT + t * 4];
        uint2 pk; pk.x = pkh2(ev.x * sfac, ev.y * sfac); pk.y = pkh2(ev.z * sfac, ev.w * sfac);
        *(uint2*)&edl[t * 4] = pk;
    }
    int rowA = i2 * 128 + w * 32 + m;
    h16 eA = (h16)(es1[h * NT + rowA] * sfac);
    h16 eB = (h16)(es1[h * NT + rowA + 16] * sfac);
    h16x2 esvA = {eA, eA}, esvB = {eB, eB};
    const us* twA = TWb + ((size_t)(b * NT) + rowA) * NT + q * 8;
    const us* twB = twA + (size_t)16 * NT;
    int hr = t >> 2, js = t & 3;
    const us* htrow = Ht + ((size_t)(h * HD) + hr) * NT + js * 16;
    f32x4 acc[2][4];
    #pragma unroll
    for (int ti = 0; ti < 2; ti++)
        #pragma unroll
        for (int ot = 0; ot < 4; ot++) acc[ti][ot] = (f32x4){0.f, 0.f, 0.f, 0.f};
    f32x4 acc1[2] = {(f32x4){0.f, 0.f, 0.f, 0.f}, (f32x4){0.f, 0.f, 0.f, 0.f}};
    h16 ov = (m == 0) ? (h16)1.0f : (h16)0.0f;
    half8 bones = {ov, ov, ov, ov, ov, ov, ov, ov};
    uint4 H0 = *(const uint4*)htrow, H1 = *(const uint4*)(htrow + 8);
    *(uint4*)&Hs[0][hr * 72 + js * 16] = H0;
    *(uint4*)&Hs[0][hr * 72 + js * 16 + 8] = H1;
    H0 = *(const uint4*)(htrow + 64); H1 = *(const uint4*)(htrow + 72);
    uint4 TA0 = *(const uint4*)twA,        TA1 = *(const uint4*)(twA + 32);
    uint4 TB0 = *(const uint4*)twB,        TB1 = *(const uint4*)(twB + 32);
    __syncthreads();
    for (int it = 0; it < 16; it++) {
        int cur = it & 1, nxt = cur ^ 1;
        int j0 = it * 64;
        uint4 nH0, nH1, nA0, nA1, nB0, nB1;
        if (it < 14) {
            nH0 = *(const uint4*)(htrow + j0 + 128);
            nH1 = *(const uint4*)(htrow + j0 + 136);
        }
        if (it < 15) {
            nA0 = *(const uint4*)(twA + j0 + 64);  nA1 = *(const uint4*)(twA + j0 + 96);
            nB0 = *(const uint4*)(twB + j0 + 64);  nB1 = *(const uint4*)(twB + j0 + 96);
        }
        uint4 D0 = *(const uint4*)&edl[j0 + q * 8];
        uint4 D1 = *(const uint4*)&edl[j0 + 32 + q * 8];
        half8 pA0 = p_frag(TA0, D0, esvA);
        half8 pA1 = p_frag(TA1, D1, esvA);
        half8 pB0 = p_frag(TB0, D0, esvB);
        half8 pB1 = p_frag(TB1, D1, esvB);
        __syncthreads();
        if (it < 15) {
            *(uint4*)&Hs[nxt][hr * 72 + js * 16] = H0;
            *(uint4*)&Hs[nxt][hr * 72 + js * 16 + 8] = H1;
        }
        const us* Hc = Hs[cur];
        #pragma unroll
        for (int ot = 0; ot < 4; ot++) {
            half8 bv0 = *(const half8*)&Hc[(ot * 16 + m) * 72 + q * 8];
            half8 bv1 = *(const half8*)&Hc[(ot * 16 + m) * 72 + 32 + q * 8];
            acc[0][ot] = __builtin_amdgcn_mfma_f32_16x16x32_f16(pA0, bv0, acc[0][ot], 0, 0, 0);
            acc[0][ot] = __builtin_amdgcn_mfma_f32_16x16x32_f16(pA1, bv1, acc[0][ot], 0, 0, 0);
            acc[1][ot] = __builtin_amdgcn_mfma_f32_16x16x32_f16(pB0, bv0, acc[1][ot], 0, 0, 0);
            acc[1][ot] = __builtin_amdgcn_mfma_f32_16x16x32_f16(pB1, bv1, acc[1][ot], 0, 0, 0);
        }
        acc1[0] = __builtin_amdgcn_mfma_f32_16x16x32_f16(pA0, bones, acc1[0], 0, 0, 0);
        acc1[0] = __builtin_amdgcn_mfma_f32_16x16x32_f16(pA1, bones, acc1[0], 0, 0, 0);
        acc1[1] = __builtin_amdgcn_mfma_f32_16x16x32_f16(pB0, bones, acc1[1], 0, 0, 0);
        acc1[1] = __builtin_amdgcn_mfma_f32_16x16x32_f16(pB1, bones, acc1[1], 0, 0, 0);
        if (it < 14) { H0 = nH0; H1 = nH1; }
        if (it < 15) { TA0 = nA0; TA1 = nA1; TB0 = nB0; TB1 = nB1; }
    }
    if (m == 0) {
        #pragma unroll
        for (int rr = 0; rr < 4; rr++) {
            invl_s[w * 32 + q * 4 + rr]      = 1.f / acc1[0][rr];
            invl_s[w * 32 + 16 + q * 4 + rr] = 1.f / acc1[1][rr];
        }
    }
    __syncthreads();
    size_t rbase = (size_t)(b * NT + i2 * 128);
    #pragma unroll
    for (int ti = 0; ti < 2; ti++) {
        #pragma unroll
        for (int ot = 0; ot < 4; ot++) {
            int col = h * HD + ot * 16 + m;
            #pragma unroll
            for (int rr = 0; rr < 4; rr++) {
                int rloc = w * 32 + ti * 16 + q * 4 + rr;
                float v = acc[ti][ot][rr] * invl_s[rloc];
                v = v > 0.f ? v : (__expf(v) - 1.f);
                node1b[(rbase + rloc) * HID + col] = f2h(v);
            }
        }
    }
}

// ============ kctx: layer-2 attention via PV associativity; atomic ctx accumulate ======
__global__ __launch_bounds__(256) void kctx(const us* __restrict__ TWb, const us* __restrict__ node1b,
                                            const us* __restrict__ VAVS, const float* __restrict__ part,
                                            const int* __restrict__ topic_ids,
                                            float* __restrict__ ctx, float* __restrict__ pl) {
    int n = blockIdx.x;          // 256: b = n&7, jb = n>>3 (32 rows each)
    int b = n & 7, jb = n >> 3;
    int t = threadIdx.x;
    __shared__ __align__(16) us n1s[32 * 520];
    __shared__ __align__(16) us vvs[16 * 520];
    __shared__ __align__(16) us qrow[HID];
    __shared__ float Ps[8][33];
    __shared__ float es2q[8];
    __shared__ float reds[256];
    int qi = topic_ids[b];
    {
        float pm = fmaxf(fmaxf(part[t * 4], part[t * 4 + 1]), fmaxf(part[t * 4 + 2], part[t * 4 + 3]));
        reds[t] = pm; __syncthreads();
        for (int s = 128; s > 0; s >>= 1) { if (t < s) reds[t] = fmaxf(reds[t], reds[t + s]); __syncthreads(); }
    }
    float sfac = exp2f(-reds[0] * (0.1f * LOG2E));
    {   // stage node1 tile [32][512]
        int row = t >> 3, c = (t & 7) * 64;
        const uint4* src = (const uint4*)(node1b + ((size_t)(b * NT) + jb * 32 + row) * HID + c);
        uint4* dst = (uint4*)&n1s[row * 520 + c];
        #pragma unroll
        for (int k = 0; k < 8; k++) dst[k] = src[k];
    }
    {   // stage VAVS [16][512]
        int row = t >> 4, c = (t & 15) * 32;
        const uint4* src = (const uint4*)(VAVS + (size_t)row * HID + c);
        uint4* dst = (uint4*)&vvs[row * 520 + c];
        dst[0] = src[0]; dst[1] = src[1]; dst[2] = src[2]; dst[3] = src[3];
    }
    if (t < 32) {   // stage node1 row qi
        const uint4* src = (const uint4*)(node1b + ((size_t)(b * NT) + qi) * HID + t * 16);
        *(uint4*)&qrow[t * 16] = src[0];
        *(uint4*)&qrow[t * 16 + 8] = src[1];
    }
    __syncthreads();
    {   // es2q[h] = sum_i qrow[i]*vs[h][i]
        int h = t >> 5, li = t & 31;
        float s = 0.f;
        #pragma unroll 4
        for (int ii = 0; ii < 16; ii++) {
            int i = li * 16 + ii;
            s = fmaf(h2f(qrow[i]), h2f(vvs[(8 + h) * 520 + i]), s);
        }
        #pragma unroll
        for (int mask = 1; mask < 32; mask <<= 1) s += __shfl_xor(s, mask);
        if (li == 0) es2q[h] = s;
    }
    __syncthreads();
    int l = t & 63, w = t >> 6, m = l & 15, q = l >> 4;
    if (w < 2) {   // ed via MFMA: [32 j] x [16 n], K=512
        f32x4 acc = (f32x4){0.f, 0.f, 0.f, 0.f};
        #pragma unroll
        for (int kt = 0; kt < 16; kt++) {
            half8 a = *(const half8*)&n1s[(w * 16 + m) * 520 + kt * 32 + q * 8];
            half8 bv = *(const half8*)&vvs[m * 520 + kt * 32 + q * 8];
            acc = __builtin_amdgcn_mfma_f32_16x16x32_f16(a, bv, acc, 0, 0, 0);
        }
        if (m < 8) {   // P[h=m][j]
            const us* twq = TWb + ((size_t)(b * NT) + qi) * NT + jb * 32;
            float esv = es2q[m];
            #pragma unroll
            for (int r = 0; r < 4; r++) {
                int j = w * 16 + q * 4 + r;
                float e = esv + acc[r];
                e = fmaxf(e, 0.2f * e);
                float twu = h2f(twq[j]);
                float p = fmaxf(exp2f(twu * sfac * e), 0.f);   // NaN -> 0
                Ps[m][j] = p;
            }
        }
    }
    __syncthreads();
    {   // pl[b][h][jb]
        int h = t >> 5, j = t & 31;
        float s = Ps[h][j];
        #pragma unroll
        for (int mask = 1; mask < 32; mask <<= 1) s += __shfl_xor(s, mask);
        if (j == 0) pl[((size_t)b * NH + h) * 32 + jb] = s;
    }
    // partial ctx: thread owns o pair (t*2, t*2+1); accumulate via device atomics
    float ac[8][2];
    #pragma unroll
    for (int h = 0; h < 8; h++) { ac[h][0] = 0.f; ac[h][1] = 0.f; }
    for (int j = 0; j < 32; j++) {
        unsigned int uv = *(const unsigned int*)&n1s[j * 520 + t * 2];
        h16x2 hv = __builtin_bit_cast(h16x2, uv);
        float f0 = (float)hv.x, f1 = (float)hv.y;
        #pragma unroll
        for (int h = 0; h < 8; h++) {
            float p = Ps[h][j];
            ac[h][0] = fmaf(p, f0, ac[h][0]);
            ac[h][1] = fmaf(p, f1, ac[h][1]);
        }
    }
    float* cp = ctx + ((size_t)b * NH) * HID;
    #pragma unroll
    for (int h = 0; h < 8; h++) {
        atomicAdd(&cp[h * HID + t * 2], ac[h][0]);
        atomicAdd(&cp[h * HID + t * 2 + 1], ac[h][1]);
    }
}

// ============ kcomb: normalize ctx, @W2 (Wt2), ELU, +attract (64 blocks) ================
__global__ __launch_bounds__(256) void kcomb(const float* __restrict__ ctx, const float* __restrict__ pl,
                                             const us* __restrict__ Wt2, const float* __restrict__ attr,
                                             const float* __restrict__ aW, const float* __restrict__ ab,
                                             float* __restrict__ comb) {
    int h = blockIdx.x & 7, b = blockIdx.x >> 3;
    int t = threadIdx.x;
    __shared__ float cx[HID];
    __shared__ float ln[1];
    if (t < 32) {
        float s = pl[((size_t)b * NH + h) * 32 + t];
        #pragma unroll
        for (int mask = 1; mask < 32; mask <<= 1) s += __shfl_xor(s, mask);
        if (t == 0) ln[0] = 1.f / s;
    }
    __syncthreads();
    float li = ln[0];
    const float* cp = ctx + ((size_t)b * NH + h) * HID;
    cx[t] = cp[t] * li; cx[t + 256] = cp[t + 256] * li;
    __syncthreads();
    int o2 = t >> 2, ks = t & 3;
    const us* wrow = Wt2 + ((size_t)h * HD + o2) * HID + ks * 128;
    float s = 0.f;
    #pragma unroll 8
    for (int k = 0; k < 128; k++) s = fmaf(cx[ks * 128 + k], h2f(wrow[k]), s);
    s += __shfl_xor(s, 1); s += __shfl_xor(s, 2);
    if (ks == 0) {
        float v = s > 0.f ? s : (__expf(s) - 1.f);   // ELU
        int col = h * HD + o2;
        comb[b * HID + col] = v + attr[b] * aW[col] + ab[col];
    }
}

// ============ kfc: fc1 + relu + fc2; atomicAdd into out[b] (256 blocks) ================
__global__ __launch_bounds__(256) void kfc(const float* __restrict__ comb,
                                           const float* __restrict__ fc1W, const float* __restrict__ fc1b,
                                           const float* __restrict__ fc2W, float* __restrict__ out) {
    int kseg = blockIdx.x, b = blockIdx.y;
    int t = threadIdx.x;
    __shared__ float cs[HID];
    __shared__ float r2[256];
    cs[t] = comb[b * HID + t];
    cs[t + 256] = comb[b * HID + t + 256];
    __syncthreads();
    int kk = kseg * 16 + (t >> 4);
    int j = t & 15;
    const float* row = fc1W + (size_t)kk * HID;
    float acc = 0.f;
    #pragma unroll 8
    for (int mi = 0; mi < 32; mi++) {
        int idx = mi * 16 + j;
        acc = fmaf(cs[idx], row[idx], acc);
    }
    #pragma unroll
    for (int mask = 1; mask < 16; mask <<= 1) acc += __shfl_xor(acc, mask);
    float partv = 0.f;
    if (j == 0) {
        float hk = fmaxf(acc + fc1b[kk], 0.f);
        partv = hk * fc2W[kk];
    }
    r2[t] = partv; __syncthreads();
    for (int s = 128; s > 0; s >>= 1) { if (t < s) r2[t] += r2[t + s]; __syncthreads(); }
    if (t == 0) atomicAdd(&out[b], r2[0]);
}

extern "C" void kernel_launch(void* const* d_in, const int* in_sizes, int n_in,
                              void* d_out, int out_size, void* d_ws, size_t ws_size,
                              hipStream_t stream) {
    const int*   topic_ids = (const int*)d_in[0];
    const int*   adj       = (const int*)d_in[1];
    const float* tm        = (const float*)d_in[2];
    const float* attr      = (const float*)d_in[3];
    const float* emb       = (const float*)d_in[4];
    const float* sW        = (const float*)d_in[5];
    const float* sb        = (const float*)d_in[6];
    const float* aW        = (const float*)d_in[7];
    const float* ab        = (const float*)d_in[8];
    const float* gW        = (const float*)d_in[9];   // (2,8,512,64)
    const float* ga        = (const float*)d_in[10];  // (2,8,128,1)
    const float* fc1W      = (const float*)d_in[11];
    const float* fc1b      = (const float*)d_in[12];
    const float* fc2W      = (const float*)d_in[13];
    const float* fc2b      = (const float*)d_in[14];
    float* out = (float*)d_out;

    char* p = (char*)d_ws;
    us* TWb    = (us*)p; p += sizeof(us) * (size_t)NB * NT * NT;        // 16.8 MB
    us* node0b = (us*)p; p += sizeof(us) * (size_t)NT * HID;            // 1 MB
    us* Wt     = (us*)p; p += sizeof(us) * (size_t)2 * NH * HD * HID;   // 1 MB
    us* Ht1    = (us*)p; p += sizeof(us) * (size_t)HID * NT;            // 1 MB
    us* node1b = (us*)p; p += sizeof(us) * (size_t)NB * NT * HID;       // 8 MB
    us* VAVS   = (us*)p; p += sizeof(us) * (size_t)16 * HID;            // 16 KB
    float* es1  = (float*)p; p += sizeof(float) * NH * NT;
    float* ed1  = (float*)p; p += sizeof(float) * NH * NT;
    float* ctx  = (float*)p; p += sizeof(float) * (size_t)NB * NH * HID;  // 128 KB
    float* pl   = (float*)p; p += sizeof(float) * NB * NH * 32;
    float* comb = (float*)p; p += sizeof(float) * NB * HID;
    float* part = (float*)p; p += sizeof(float) * 1024;

    kprep<<<1344, 256, 0, stream>>>(tm, adj, part, TWb, emb, sW, sb, node0b, gW, Wt, ga, VAVS,
                                    ctx, fc2b, out);
    kgemm1<<<128, 256, 0, stream>>>(node0b, Wt, ga, Ht1, es1, ed1);
    kattn1<<<512, 256, 0, stream>>>(TWb, Ht1, es1, ed1, part, node1b);
    kctx<<<256, 256, 0, stream>>>(TWb, node1b, VAVS, part, topic_ids, ctx, pl);
    kcomb<<<64, 256, 0, stream>>>(ctx, pl, Wt + (size_t)NH * HD * HID, attr, aW, ab, comb);
    kfc<<<dim3(32, NB), 256, 0, stream>>>(comb, fc1W, fc1b, fc2W, out);
}

// Round 11
// 174.930 us; speedup vs baseline: 1.4279x; 1.0372x over previous
//
#include <hip/hip_runtime.h>

#define NT 1024      // N_TOPICS
#define TD 128       // TOPIC_DIM
#define HID 512      // HIDDEN
#define NH 8         // N_HEADS
#define HD 64        // HEAD_DIM
#define NB 8         // BATCH

typedef unsigned short us;
typedef _Float16 h16;
typedef h16 half8 __attribute__((ext_vector_type(8)));
typedef h16 h16x2 __attribute__((ext_vector_type(2)));
typedef float f32x4 __attribute__((ext_vector_type(4)));

#define LOG2E 1.44269504f

extern "C" __device__ _Float16 __ocml_exp2_f16(_Float16);

__device__ __forceinline__ us f2h(float x) { return __builtin_bit_cast(us, (h16)x); }
__device__ __forceinline__ float h2f(us s) { return (float)__builtin_bit_cast(h16, s); }
__device__ __forceinline__ unsigned int pkh2(float a, float b) {
    auto v = __builtin_amdgcn_cvt_pkrtz(a, b);
    return __builtin_bit_cast(unsigned int, v);
}

// ============ kprep: fused max-scan + TWu (0-1023) | node0 GEMM (1024-1151)
//              | gW transpose (1152-1279; block 1152 inits out) | VAVS (1280-1343)
// TWu = f16(exp2(tm*0.1*log2e)*log2e) or NaN where adj==0; tw = TWu*sfac.
// VAVS[n][i]: n<8 -> W2_n @ a_dst (ed2); n>=8 -> W2_(n-8) @ a_src (es2q).
__global__ __launch_bounds__(256) void kprep(const float* __restrict__ tm, const int* __restrict__ adj,
                                             float* __restrict__ part, us* __restrict__ TWb,
                                             const float* __restrict__ emb, const float* __restrict__ sW,
                                             const float* __restrict__ sb, us* __restrict__ node0b,
                                             const float* __restrict__ gW, us* __restrict__ Wt,
                                             const float* __restrict__ ga, us* __restrict__ VAVS,
                                             const float* __restrict__ fc2b, float* __restrict__ out) {
    __shared__ __align__(16) float smf[8768];
    int bx = blockIdx.x, t = threadIdx.x;
    if (bx < 1024) {
        const float4* tm4 = (const float4*)tm;
        const int4* ad4 = (const int4*)adj;
        size_t base = (size_t)bx * 256 + t;
        const float C = 0.1f * LOG2E;
        const float NANF = __uint_as_float(0x7FC00000u);
        float m = -1e30f;
        #pragma unroll
        for (int k = 0; k < 8; k++) {
            size_t fi = base + (size_t)k * 262144;
            float4 v = tm4[fi];
            int4 av = ad4[fi];
            m = fmaxf(m, fmaxf(fmaxf(v.x, v.y), fmaxf(v.z, v.w)));
            float w0 = exp2f(v.x * C) * LOG2E;
            float w1 = exp2f(v.y * C) * LOG2E;
            float w2 = exp2f(v.z * C) * LOG2E;
            float w3 = exp2f(v.w * C) * LOG2E;
            w0 = av.x ? w0 : NANF;
            w1 = av.y ? w1 : NANF;
            w2 = av.z ? w2 : NANF;
            w3 = av.w ? w3 : NANF;
            uint2 pk;
            pk.x = pkh2(w0, w1);
            pk.y = pkh2(w2, w3);
            *(uint2*)&TWb[fi * 4] = pk;
        }
        smf[t] = m; __syncthreads();
        for (int s = 128; s > 0; s >>= 1) { if (t < s) smf[t] = fmaxf(smf[t], smf[t + s]); __syncthreads(); }
        if (t == 0) part[bx] = smf[0];
    } else if (bx < 1152) {
        int g = bx - 1024; int iblk = g & 15, oseg = g >> 4;
        us* As = (us*)smf;              // [64][136]
        us* Bs = (us*)smf + 64 * 136;
        const float4* esrc = (const float4*)(emb + (size_t)iblk * 64 * TD);
        const float4* wsrc = (const float4*)(sW + (size_t)oseg * 64 * TD);
        #pragma unroll
        for (int rep = 0; rep < 8; rep++) {
            int f = rep * 256 + t;
            int row = f >> 5, c4 = f & 31;
            float4 av = esrc[f];
            float4 bv = wsrc[f];
            uint2 pa, pb;
            pa.x = pkh2(av.x, av.y); pa.y = pkh2(av.z, av.w);
            pb.x = pkh2(bv.x, bv.y); pb.y = pkh2(bv.z, bv.w);
            *(uint2*)&As[row * 136 + c4 * 4] = pa;
            *(uint2*)&Bs[row * 136 + c4 * 4] = pb;
        }
        __syncthreads();
        int l = t & 63, w = t >> 6, m = l & 15, q = l >> 4;
        f32x4 acc[4];
        #pragma unroll
        for (int ot = 0; ot < 4; ot++) acc[ot] = (f32x4){0.f, 0.f, 0.f, 0.f};
        #pragma unroll
        for (int ks = 0; ks < 4; ks++) {
            half8 a = *(const half8*)&As[(w * 16 + m) * 136 + ks * 32 + q * 8];
            #pragma unroll
            for (int ot = 0; ot < 4; ot++) {
                half8 b = *(const half8*)&Bs[(ot * 16 + m) * 136 + ks * 32 + q * 8];
                acc[ot] = __builtin_amdgcn_mfma_f32_16x16x32_f16(a, b, acc[ot], 0, 0, 0);
            }
        }
        #pragma unroll
        for (int ot = 0; ot < 4; ot++) {
            int col = oseg * 64 + ot * 16 + m;
            float sbv = sb[col];
            #pragma unroll
            for (int rr = 0; rr < 4; rr++) {
                int rowi = iblk * 64 + w * 16 + q * 4 + rr;
                node0b[(size_t)rowi * HID + col] = f2h(acc[ot][rr] + sbv);
            }
        }
    } else if (bx < 1280) {
        // Wt[lh][o][k] = f16(gW[lh][k][o]); lh in [0,16), kt in [0,8)
        int g = bx - 1152; int lh = g >> 3, kt = g & 7;
        if (g == 0 && t < NB) out[t] = fc2b[0];
        float* tile = smf;   // [64][65]
        const float4* src = (const float4*)(gW + ((size_t)lh * HID + kt * 64) * HD);
        #pragma unroll
        for (int rep = 0; rep < 4; rep++) {
            int f = rep * 256 + t;
            float4 v = src[f];
            int row = f >> 4, col = (f & 15) * 4;
            float* d = tile + row * 65 + col;
            d[0] = v.x; d[1] = v.y; d[2] = v.z; d[3] = v.w;
        }
        __syncthreads();
        int o = t >> 2, ks = (t & 3) * 16;
        us pk[16];
        #pragma unroll
        for (int j = 0; j < 16; j++) pk[j] = f2h(tile[(ks + j) * 65 + o]);
        us* dst = Wt + (size_t)lh * HD * HID + (size_t)o * HID + kt * 64 + ks;
        *(uint4*)dst = *(uint4*)pk;
        *(uint4*)(dst + 8) = *(uint4*)&pk[8];
    } else {
        // VAVS: 64 blocks: h = g>>3, iseg = g&7; t<128: sel = t>>6 (0: va/dst, 1: vs/src)
        int g = bx - 1280; int h = g >> 3, iseg = g & 7;
        if (t < 128) {
            int sel = t >> 6, il = t & 63;
            int i = iseg * 64 + il;
            const float* W2row = gW + (size_t)NH * HID * HD + ((size_t)h * HID + i) * HD;
            const float* a2 = ga + NH * 2 * HD + h * 2 * HD;
            const float* av = sel ? a2 : (a2 + HD);   // vs: a_src; va: a_dst
            float s = 0.f;
            #pragma unroll 8
            for (int o = 0; o < HD; o++) s = fmaf(W2row[o], av[o], s);
            VAVS[(size_t)(sel * 8 + h) * HID + i] = f2h(s);
        }
    }
}

// ============ shared GEMM body (layer-1) ================================================
__device__ __forceinline__ void gemm_body(const us* __restrict__ A, const us* __restrict__ W,
                                          const float* __restrict__ gav,
                                          us* __restrict__ outT,
                                          float* __restrict__ esO, float* __restrict__ edO,
                                          int iblk, int b, int h, int t, us* sm) {
    us* As = sm;              // [2][64*72]
    us* Bs = sm + 2 * 4608;
    int row = t >> 2, ks = t & 3;
    int l = t & 63, w = t >> 6, m = l & 15, q = l >> 4;
    size_t arow0 = (size_t)(b * NT + iblk * 64);
    const us* ar = A + (arow0 + row) * HID + ks * 16;
    const us* br = W + ((size_t)(h * HD + row)) * HID + ks * 16;
    f32x4 acc[4];
    #pragma unroll
    for (int ot = 0; ot < 4; ot++) acc[ot] = (f32x4){0.f, 0.f, 0.f, 0.f};
    {
        uint4 x0 = *(const uint4*)ar, x1 = *(const uint4*)(ar + 8);
        uint4 y0 = *(const uint4*)br, y1 = *(const uint4*)(br + 8);
        *(uint4*)&As[row * 72 + ks * 16] = x0; *(uint4*)&As[row * 72 + ks * 16 + 8] = x1;
        *(uint4*)&Bs[row * 72 + ks * 16] = y0; *(uint4*)&Bs[row * 72 + ks * 16 + 8] = y1;
    }
    uint4 a0 = *(const uint4*)(ar + 64), a1 = *(const uint4*)(ar + 72);
    uint4 b0 = *(const uint4*)(br + 64), b1 = *(const uint4*)(br + 72);
    for (int it = 0; it < 8; it++) {
        int cur = it & 1, nxt = cur ^ 1;
        uint4 na0, na1, nb0, nb1;
        if (it < 6) {
            int k0 = (it + 2) * 64;
            na0 = *(const uint4*)(ar + k0); na1 = *(const uint4*)(ar + k0 + 8);
            nb0 = *(const uint4*)(br + k0); nb1 = *(const uint4*)(br + k0 + 8);
        }
        __syncthreads();
        if (it < 7) {
            *(uint4*)&As[nxt * 4608 + row * 72 + ks * 16] = a0;
            *(uint4*)&As[nxt * 4608 + row * 72 + ks * 16 + 8] = a1;
            *(uint4*)&Bs[nxt * 4608 + row * 72 + ks * 16] = b0;
            *(uint4*)&Bs[nxt * 4608 + row * 72 + ks * 16 + 8] = b1;
        }
        const us* Ac = As + cur * 4608; const us* Bc = Bs + cur * 4608;
        #pragma unroll
        for (int kt = 0; kt < 2; kt++) {
            half8 av = *(const half8*)&Ac[(w * 16 + m) * 72 + kt * 32 + q * 8];
            #pragma unroll
            for (int ot = 0; ot < 4; ot++) {
                half8 bv = *(const half8*)&Bc[(ot * 16 + m) * 72 + kt * 32 + q * 8];
                acc[ot] = __builtin_amdgcn_mfma_f32_16x16x32_f16(av, bv, acc[ot], 0, 0, 0);
            }
        }
        if (it < 6) { a0 = na0; a1 = na1; b0 = nb0; b1 = nb1; }
    }
    const float* gas = gav + h * 2 * HD;
    float gs[4], gd[4];
    #pragma unroll
    for (int ot = 0; ot < 4; ot++) { gs[ot] = gas[ot * 16 + m]; gd[ot] = gas[HD + ot * 16 + m]; }
    size_t ebase = ((size_t)b * NH + h) * NT + iblk * 64;
    #pragma unroll
    for (int rr = 0; rr < 4; rr++) {
        float s = 0.f, d = 0.f;
        #pragma unroll
        for (int ot = 0; ot < 4; ot++) { float v = acc[ot][rr]; s = fmaf(v, gs[ot], s); d = fmaf(v, gd[ot], d); }
        #pragma unroll
        for (int mask = 1; mask < 16; mask <<= 1) { s += __shfl_xor(s, mask); d += __shfl_xor(d, mask); }
        if (m == 0) {
            int rowi = w * 16 + q * 4 + rr;
            esO[ebase + rowi] = s;
            edO[ebase + rowi] = d;
        }
    }
    #pragma unroll
    for (int ot = 0; ot < 4; ot++) {
        int col = h * HD + ot * 16 + m;
        #pragma unroll
        for (int rr = 0; rr < 4; rr++) {
            int i_loc = w * 16 + q * 4 + rr;
            outT[(size_t)col * NT + iblk * 64 + i_loc] = f2h(acc[ot][rr]);
        }
    }
}

// ============ layer-1 GEMM (128 blocks) ================================================
__global__ __launch_bounds__(256) void kgemm1(const us* __restrict__ node0b, const us* __restrict__ Wt,
                                              const float* __restrict__ ga, us* __restrict__ Ht1,
                                              float* __restrict__ es1, float* __restrict__ ed1) {
    __shared__ __align__(16) us sm[4 * 4608];
    int g = blockIdx.x;
    gemm_body(node0b, Wt, ga, Ht1, es1, ed1, g & 15, 0, g >> 4, threadIdx.x, sm);
}

// ============ layer-1 attention ========================================================
__device__ __forceinline__ unsigned int p_word_fly(unsigned int tw, unsigned int ed, h16x2 es) {
    h16x2 t = __builtin_bit_cast(h16x2, tw);
    h16x2 d = __builtin_bit_cast(h16x2, ed);
    h16x2 e = es + d;
    h16x2 lk = e * (h16)0.2f;
    h16x2 el = __builtin_elementwise_max(e, lk);
    h16x2 mm = t * el;
    h16x2 p;
    p.x = __ocml_exp2_f16(mm.x);
    p.y = __ocml_exp2_f16(mm.y);
    h16x2 z = {(h16)0.0f, (h16)0.0f};
    h16x2 r = __builtin_elementwise_max(p, z);
    return __builtin_bit_cast(unsigned int, r);
}

__device__ __forceinline__ half8 p_frag(uint4 T, uint4 D, h16x2 es) {
    uint4 r;
    r.x = p_word_fly(T.x, D.x, es);
    r.y = p_word_fly(T.y, D.y, es);
    r.z = p_word_fly(T.z, D.z, es);
    r.w = p_word_fly(T.w, D.w, es);
    return __builtin_bit_cast(half8, r);
}

__global__ __launch_bounds__(256) void kattn1(const us* __restrict__ TWb, const us* __restrict__ Ht,
                                              const float* __restrict__ es1, const float* __restrict__ ed1,
                                              const float* __restrict__ part, us* __restrict__ node1b) {
    int n = blockIdx.x;               // 512 blocks; b=n&7 -> one batch per XCD
    int b = n & 7, k = n >> 3;
    int i2 = k & 7, h = k >> 3;
    int t = threadIdx.x;
    __shared__ __align__(16) us Hs[2][64 * 72];
    __shared__ __align__(16) us edl[NT];
    __shared__ float invl_s[128];
    __shared__ float reds[256];
    int l = t & 63, w = t >> 6, m = l & 15, q = l >> 4;
    {
        float pm = fmaxf(fmaxf(part[t * 4], part[t * 4 + 1]), fmaxf(part[t * 4 + 2], part[t * 4 + 3]));
        reds[t] = pm; __syncthreads();
        for (int s = 128; s > 0; s >>= 1) { if (t < s) reds[t] = fmaxf(reds[t], reds[t + s]); __syncthreads(); }
    }
    float sfac = exp2f(-reds[0] * (0.1f * LOG2E));
    {
        float4 ev = *(const float4*)&ed1[h * NT + t * 4];
        uint2 pk; pk.x = pkh2(ev.x * sfac, ev.y * sfac); pk.y = pkh2(ev.z * sfac, ev.w * sfac);
        *(uint2*)&edl[t * 4] = pk;
    }
    int rowA = i2 * 128 + w * 32 + m;
    h16 eA = (h16)(es1[h * NT + rowA] * sfac);
    h16 eB = (h16)(es1[h * NT + rowA + 16] * sfac);
    h16x2 esvA = {eA, eA}, esvB = {eB, eB};
    const us* twA = TWb + ((size_t)(b * NT) + rowA) * NT + q * 8;
    const us* twB = twA + (size_t)16 * NT;
    int hr = t >> 2, js = t & 3;
    const us* htrow = Ht + ((size_t)(h * HD) + hr) * NT + js * 16;
    f32x4 acc[2][4];
    #pragma unroll
    for (int ti = 0; ti < 2; ti++)
        #pragma unroll
        for (int ot = 0; ot < 4; ot++) acc[ti][ot] = (f32x4){0.f, 0.f, 0.f, 0.f};
    f32x4 acc1[2] = {(f32x4){0.f, 0.f, 0.f, 0.f}, (f32x4){0.f, 0.f, 0.f, 0.f}};
    h16 ov = (m == 0) ? (h16)1.0f : (h16)0.0f;
    half8 bones = {ov, ov, ov, ov, ov, ov, ov, ov};
    uint4 H0 = *(const uint4*)htrow, H1 = *(const uint4*)(htrow + 8);
    *(uint4*)&Hs[0][hr * 72 + js * 16] = H0;
    *(uint4*)&Hs[0][hr * 72 + js * 16 + 8] = H1;
    H0 = *(const uint4*)(htrow + 64); H1 = *(const uint4*)(htrow + 72);
    uint4 TA0 = *(const uint4*)twA,        TA1 = *(const uint4*)(twA + 32);
    uint4 TB0 = *(const uint4*)twB,        TB1 = *(const uint4*)(twB + 32);
    __syncthreads();
    for (int it = 0; it < 16; it++) {
        int cur = it & 1, nxt = cur ^ 1;
        int j0 = it * 64;
        uint4 nH0, nH1, nA0, nA1, nB0, nB1;
        if (it < 14) {
            nH0 = *(const uint4*)(htrow + j0 + 128);
            nH1 = *(const uint4*)(htrow + j0 + 136);
        }
        if (it < 15) {
            nA0 = *(const uint4*)(twA + j0 + 64);  nA1 = *(const uint4*)(twA + j0 + 96);
            nB0 = *(const uint4*)(twB + j0 + 64);  nB1 = *(const uint4*)(twB + j0 + 96);
        }
        uint4 D0 = *(const uint4*)&edl[j0 + q * 8];
        uint4 D1 = *(const uint4*)&edl[j0 + 32 + q * 8];
        half8 pA0 = p_frag(TA0, D0, esvA);
        half8 pA1 = p_frag(TA1, D1, esvA);
        half8 pB0 = p_frag(TB0, D0, esvB);
        half8 pB1 = p_frag(TB1, D1, esvB);
        __syncthreads();
        if (it < 15) {
            *(uint4*)&Hs[nxt][hr * 72 + js * 16] = H0;
            *(uint4*)&Hs[nxt][hr * 72 + js * 16 + 8] = H1;
        }
        const us* Hc = Hs[cur];
        #pragma unroll
        for (int ot = 0; ot < 4; ot++) {
            half8 bv0 = *(const half8*)&Hc[(ot * 16 + m) * 72 + q * 8];
            half8 bv1 = *(const half8*)&Hc[(ot * 16 + m) * 72 + 32 + q * 8];
            acc[0][ot] = __builtin_amdgcn_mfma_f32_16x16x32_f16(pA0, bv0, acc[0][ot], 0, 0, 0);
            acc[0][ot] = __builtin_amdgcn_mfma_f32_16x16x32_f16(pA1, bv1, acc[0][ot], 0, 0, 0);
            acc[1][ot] = __builtin_amdgcn_mfma_f32_16x16x32_f16(pB0, bv0, acc[1][ot], 0, 0, 0);
            acc[1][ot] = __builtin_amdgcn_mfma_f32_16x16x32_f16(pB1, bv1, acc[1][ot], 0, 0, 0);
        }
        acc1[0] = __builtin_amdgcn_mfma_f32_16x16x32_f16(pA0, bones, acc1[0], 0, 0, 0);
        acc1[0] = __builtin_amdgcn_mfma_f32_16x16x32_f16(pA1, bones, acc1[0], 0, 0, 0);
        acc1[1] = __builtin_amdgcn_mfma_f32_16x16x32_f16(pB0, bones, acc1[1], 0, 0, 0);
        acc1[1] = __builtin_amdgcn_mfma_f32_16x16x32_f16(pB1, bones, acc1[1], 0, 0, 0);
        if (it < 14) { H0 = nH0; H1 = nH1; }
        if (it < 15) { TA0 = nA0; TA1 = nA1; TB0 = nB0; TB1 = nB1; }
    }
    if (m == 0) {
        #pragma unroll
        for (int rr = 0; rr < 4; rr++) {
            invl_s[w * 32 + q * 4 + rr]      = 1.f / acc1[0][rr];
            invl_s[w * 32 + 16 + q * 4 + rr] = 1.f / acc1[1][rr];
        }
    }
    __syncthreads();
    size_t rbase = (size_t)(b * NT + i2 * 128);
    #pragma unroll
    for (int ti = 0; ti < 2; ti++) {
        #pragma unroll
        for (int ot = 0; ot < 4; ot++) {
            int col = h * HD + ot * 16 + m;
            #pragma unroll
            for (int rr = 0; rr < 4; rr++) {
                int rloc = w * 32 + ti * 16 + q * 4 + rr;
                float v = acc[ti][ot][rr] * invl_s[rloc];
                v = v > 0.f ? v : (__expf(v) - 1.f);
                node1b[(rbase + rloc) * HID + col] = f2h(v);
            }
        }
    }
}

// ============ kctx: layer-2 attention via PV associativity ==============================
// Per (b, jb): ed[h][j] = n1[j]·va[h] (MFMA), P row-qi slice, partial ctx = P @ n1.
__global__ __launch_bounds__(256) void kctx(const us* __restrict__ TWb, const us* __restrict__ node1b,
                                            const us* __restrict__ VAVS, const float* __restrict__ part,
                                            const int* __restrict__ topic_ids,
                                            float* __restrict__ ctxp, float* __restrict__ pl) {
    int n = blockIdx.x;          // 256: b = n&7, jb = n>>3 (32 rows each)
    int b = n & 7, jb = n >> 3;
    int t = threadIdx.x;
    __shared__ __align__(16) us n1s[32 * 520];
    __shared__ __align__(16) us vvs[16 * 520];
    __shared__ __align__(16) us qrow[HID];
    __shared__ float Ps[8][33];
    __shared__ float es2q[8];
    __shared__ float reds[256];
    int qi = topic_ids[b];
    {
        float pm = fmaxf(fmaxf(part[t * 4], part[t * 4 + 1]), fmaxf(part[t * 4 + 2], part[t * 4 + 3]));
        reds[t] = pm; __syncthreads();
        for (int s = 128; s > 0; s >>= 1) { if (t < s) reds[t] = fmaxf(reds[t], reds[t + s]); __syncthreads(); }
    }
    float sfac = exp2f(-reds[0] * (0.1f * LOG2E));
    {   // stage node1 tile [32][512]
        int row = t >> 3, c = (t & 7) * 64;
        const uint4* src = (const uint4*)(node1b + ((size_t)(b * NT) + jb * 32 + row) * HID + c);
        uint4* dst = (uint4*)&n1s[row * 520 + c];
        #pragma unroll
        for (int k = 0; k < 8; k++) dst[k] = src[k];
    }
    {   // stage VAVS [16][512]
        int row = t >> 4, c = (t & 15) * 32;
        const uint4* src = (const uint4*)(VAVS + (size_t)row * HID + c);
        uint4* dst = (uint4*)&vvs[row * 520 + c];
        dst[0] = src[0]; dst[1] = src[1]; dst[2] = src[2]; dst[3] = src[3];
    }
    if (t < 32) {   // stage node1 row qi
        const uint4* src = (const uint4*)(node1b + ((size_t)(b * NT) + qi) * HID + t * 16);
        *(uint4*)&qrow[t * 16] = src[0];
        *(uint4*)&qrow[t * 16 + 8] = src[1];
    }
    __syncthreads();
    {   // es2q[h] = sum_i qrow[i]*vs[h][i]
        int h = t >> 5, li = t & 31;
        float s = 0.f;
        #pragma unroll 4
        for (int ii = 0; ii < 16; ii++) {
            int i = li * 16 + ii;
            s = fmaf(h2f(qrow[i]), h2f(vvs[(8 + h) * 520 + i]), s);
        }
        #pragma unroll
        for (int mask = 1; mask < 32; mask <<= 1) s += __shfl_xor(s, mask);
        if (li == 0) es2q[h] = s;
    }
    __syncthreads();
    int l = t & 63, w = t >> 6, m = l & 15, q = l >> 4;
    if (w < 2) {   // ed via MFMA: [32 j] x [16 n], K=512
        f32x4 acc = (f32x4){0.f, 0.f, 0.f, 0.f};
        #pragma unroll
        for (int kt = 0; kt < 16; kt++) {
            half8 a = *(const half8*)&n1s[(w * 16 + m) * 520 + kt * 32 + q * 8];
            half8 bv = *(const half8*)&vvs[m * 520 + kt * 32 + q * 8];
            acc = __builtin_amdgcn_mfma_f32_16x16x32_f16(a, bv, acc, 0, 0, 0);
        }
        if (m < 8) {   // P[h=m][j]
            const us* twq = TWb + ((size_t)(b * NT) + qi) * NT + jb * 32;
            float esv = es2q[m];
            #pragma unroll
            for (int r = 0; r < 4; r++) {
                int j = w * 16 + q * 4 + r;
                float e = esv + acc[r];
                e = fmaxf(e, 0.2f * e);
                float twu = h2f(twq[j]);
                float p = fmaxf(exp2f(twu * sfac * e), 0.f);   // NaN -> 0
                Ps[m][j] = p;
            }
        }
    }
    __syncthreads();
    {   // pl[b][h][jb]
        int h = t >> 5, j = t & 31;
        float s = Ps[h][j];
        #pragma unroll
        for (int mask = 1; mask < 32; mask <<= 1) s += __shfl_xor(s, mask);
        if (j == 0) pl[((size_t)b * NH + h) * 32 + jb] = s;
    }
    // partial ctx: thread owns o pair (t*2, t*2+1)
    float ac[8][2];
    #pragma unroll
    for (int h = 0; h < 8; h++) { ac[h][0] = 0.f; ac[h][1] = 0.f; }
    for (int j = 0; j < 32; j++) {
        unsigned int uv = *(const unsigned int*)&n1s[j * 520 + t * 2];
        h16x2 hv = __builtin_bit_cast(h16x2, uv);
        float f0 = (float)hv.x, f1 = (float)hv.y;
        #pragma unroll
        for (int h = 0; h < 8; h++) {
            float p = Ps[h][j];
            ac[h][0] = fmaf(p, f0, ac[h][0]);
            ac[h][1] = fmaf(p, f1, ac[h][1]);
        }
    }
    float* cp = ctxp + (((size_t)b * 32 + jb) * NH) * HID;
    #pragma unroll
    for (int h = 0; h < 8; h++) {
        float2 v; v.x = ac[h][0]; v.y = ac[h][1];
        *(float2*)&cp[h * HID + t * 2] = v;
    }
}

// ============ kcomb: reduce ctx, normalize, @W2 (Wt2), ELU, +attract ====================
__global__ __launch_bounds__(256) void kcomb(const float* __restrict__ ctxp, const float* __restrict__ pl,
                                             const us* __restrict__ Wt2, const float* __restrict__ attr,
                                             const float* __restrict__ aW, const float* __restrict__ ab,
                                             float* __restrict__ comb) {
    int h = blockIdx.x & 7, b = blockIdx.x >> 3;
    int t = threadIdx.x;
    __shared__ float cx[HID];
    __shared__ float ln[1];
    if (t < 32) {
        float s = pl[((size_t)b * NH + h) * 32 + t];
        #pragma unroll
        for (int mask = 1; mask < 32; mask <<= 1) s += __shfl_xor(s, mask);
        if (t == 0) ln[0] = 1.f / s;
    }
    float a0 = 0.f, a1 = 0.f;
    for (int jb = 0; jb < 32; jb++) {
        const float* cp = ctxp + (((size_t)b * 32 + jb) * NH + h) * HID;
        a0 += cp[t]; a1 += cp[t + 256];
    }
    __syncthreads();
    float li = ln[0];
    cx[t] = a0 * li; cx[t + 256] = a1 * li;
    __syncthreads();
    int o2 = t >> 2, ks = t & 3;
    const us* wrow = Wt2 + ((size_t)h * HD + o2) * HID + ks * 128;
    float s = 0.f;
    #pragma unroll 8
    for (int k = 0; k < 128; k++) s = fmaf(cx[ks * 128 + k], h2f(wrow[k]), s);
    s += __shfl_xor(s, 1); s += __shfl_xor(s, 2);
    if (ks == 0) {
        float v = s > 0.f ? s : (__expf(s) - 1.f);   // ELU
        int col = h * HD + o2;
        comb[b * HID + col] = v + attr[b] * aW[col] + ab[col];
    }
}

// ============ kfc: fc1 + relu + fc2; atomicAdd into out[b] ==============================
__global__ __launch_bounds__(256) void kfc(const float* __restrict__ comb,
                                           const float* __restrict__ fc1W, const float* __restrict__ fc1b,
                                           const float* __restrict__ fc2W, float* __restrict__ out) {
    int kseg = blockIdx.x, b = blockIdx.y;
    int t = threadIdx.x;
    __shared__ float cs[HID];
    __shared__ float r2[256];
    cs[t] = comb[b * HID + t];
    cs[t + 256] = comb[b * HID + t + 256];
    __syncthreads();
    int kk = kseg * 16 + (t >> 4);
    int j = t & 15;
    const float* row = fc1W + (size_t)kk * HID;
    float acc = 0.f;
    #pragma unroll 8
    for (int mi = 0; mi < 32; mi++) {
        int idx = mi * 16 + j;
        acc = fmaf(cs[idx], row[idx], acc);
    }
    #pragma unroll
    for (int mask = 1; mask < 16; mask <<= 1) acc += __shfl_xor(acc, mask);
    float partv = 0.f;
    if (j == 0) {
        float hk = fmaxf(acc + fc1b[kk], 0.f);
        partv = hk * fc2W[kk];
    }
    r2[t] = partv; __syncthreads();
    for (int s = 128; s > 0; s >>= 1) { if (t < s) r2[t] += r2[t + s]; __syncthreads(); }
    if (t == 0) atomicAdd(&out[b], r2[0]);
}

extern "C" void kernel_launch(void* const* d_in, const int* in_sizes, int n_in,
                              void* d_out, int out_size, void* d_ws, size_t ws_size,
                              hipStream_t stream) {
    const int*   topic_ids = (const int*)d_in[0];
    const int*   adj       = (const int*)d_in[1];
    const float* tm        = (const float*)d_in[2];
    const float* attr      = (const float*)d_in[3];
    const float* emb       = (const float*)d_in[4];
    const float* sW        = (const float*)d_in[5];
    const float* sb        = (const float*)d_in[6];
    const float* aW        = (const float*)d_in[7];
    const float* ab        = (const float*)d_in[8];
    const float* gW        = (const float*)d_in[9];   // (2,8,512,64)
    const float* ga        = (const float*)d_in[10];  // (2,8,128,1)
    const float* fc1W      = (const float*)d_in[11];
    const float* fc1b      = (const float*)d_in[12];
    const float* fc2W      = (const float*)d_in[13];
    const float* fc2b      = (const float*)d_in[14];
    float* out = (float*)d_out;

    char* p = (char*)d_ws;
    us* TWb    = (us*)p; p += sizeof(us) * (size_t)NB * NT * NT;        // 16.8 MB
    us* node0b = (us*)p; p += sizeof(us) * (size_t)NT * HID;            // 1 MB
    us* Wt     = (us*)p; p += sizeof(us) * (size_t)2 * NH * HD * HID;   // 1 MB
    us* Ht1    = (us*)p; p += sizeof(us) * (size_t)HID * NT;            // 1 MB
    us* node1b = (us*)p; p += sizeof(us) * (size_t)NB * NT * HID;       // 8 MB
    us* VAVS   = (us*)p; p += sizeof(us) * (size_t)16 * HID;            // 16 KB
    float* es1  = (float*)p; p += sizeof(float) * NH * NT;
    float* ed1  = (float*)p; p += sizeof(float) * NH * NT;
    float* ctxp = (float*)p; p += sizeof(float) * (size_t)NB * 32 * NH * HID;  // 4 MB
    float* pl   = (float*)p; p += sizeof(float) * NB * NH * 32;
    float* comb = (float*)p; p += sizeof(float) * NB * HID;
    float* part = (float*)p; p += sizeof(float) * 1024;

    kprep<<<1344, 256, 0, stream>>>(tm, adj, part, TWb, emb, sW, sb, node0b, gW, Wt, ga, VAVS, fc2b, out);
    kgemm1<<<128, 256, 0, stream>>>(node0b, Wt, ga, Ht1, es1, ed1);
    kattn1<<<512, 256, 0, stream>>>(TWb, Ht1, es1, ed1, part, node1b);
    kctx<<<256, 256, 0, stream>>>(TWb, node1b, VAVS, part, topic_ids, ctxp, pl);
    kcomb<<<64, 256, 0, stream>>>(ctxp, pl, Wt + (size_t)NH * HD * HID, attr, aW, ab, comb);
    kfc<<<dim3(32, NB), 256, 0, stream>>>(comb, fc1W, fc1b, fc2W, out);
}